// Round 4
// baseline (293.688 us; speedup 1.0000x reference)
//
#include <hip/hip_runtime.h>

// GMLLM dual-stream self-attention, MI355X/gfx950.  Round 4:
//  - attn: 64 q-rows/wave (2-wave/128-thr blocks, KT=32) -> halves LDS bytes per MFMA;
//          4 blocks/CU; register softmax kept (no-max, exact: logits bounded)
//  - proj: XCD-swizzled 1D grid (all x,z blocks of one m-tile on one XCD -> X fetched
//          once from HBM), launch_bounds(256,3)

typedef __attribute__((ext_vector_type(8))) short short8;   // 8 x bf16 (4 VGPRs) MFMA A/B frag
typedef __attribute__((ext_vector_type(4))) float floatx4;  // MFMA C/D frag

#define LOG2E 1.4426950408889634f
#define QSCL 0.18033688011112042f   /* 0.125 * log2(e) */

static constexpr int Sn = 2048, Dn = 768, Hn = 12, BHn = 48;

__device__ __forceinline__ unsigned short f2bf(float f) {
  unsigned u = __float_as_uint(f);
  u += 0x7FFFu + ((u >> 16) & 1u);          // RNE
  return (unsigned short)(u >> 16);
}

typedef const __attribute__((address_space(1))) unsigned int* gas_t;
typedef __attribute__((address_space(3))) unsigned int* las_t;
__device__ __forceinline__ void async16(const void* g, void* l) {
  // async 16B/lane global->LDS; LDS dest = wave-uniform base + lane*16
  __builtin_amdgcn_global_load_lds((gas_t)g, (las_t)l, 16, 0, 0);
}

// ---------------- cast hidden_states f32 -> bf16 (row-major [8192][768]) ----------------
__global__ void cast_hs_kernel(const float* __restrict__ in, unsigned short* __restrict__ out, int n4) {
  int i = blockIdx.x * 256 + threadIdx.x;
  if (i >= n4) return;
  float4 v = ((const float4*)in)[i];
  ushort4 o = make_ushort4(f2bf(v.x), f2bf(v.y), f2bf(v.z), f2bf(v.w));
  ((ushort4*)out)[i] = o;
}

// ---------------- cast Wq/Wk/Wv f32 -> bf16, stacked [3][768][768] ----------------
__global__ void cast_w_kernel(const float* __restrict__ w0, const float* __restrict__ w1,
                              const float* __restrict__ w2, unsigned short* __restrict__ out) {
  int i = blockIdx.x * 256 + threadIdx.x;
  const float* src = (blockIdx.y == 0) ? w0 : (blockIdx.y == 1) ? w1 : w2;
  float4 v = ((const float4*)src)[i];
  ushort4 o = make_ushort4(f2bf(v.x), f2bf(v.y), f2bf(v.z), f2bf(v.w));
  ((ushort4*)(out + (size_t)blockIdx.y * Dn * Dn))[i] = o;
}

// ---------------- pack layout_q (pre-scaled) / layout_k into upper half of Qc/Kc ----------------
__global__ void pack_layout_kernel(const float* __restrict__ lq, const float* __restrict__ lk,
                                   unsigned short* __restrict__ Qc, unsigned short* __restrict__ Kc) {
  int idx = blockIdx.x * 256 + threadIdx.x;
  const float* src = blockIdx.y ? lk : lq;
  unsigned short* dst = blockIdx.y ? Kc : Qc;
  const float sc = blockIdx.y ? 1.0f : QSCL;
  int d4 = idx & 15;
  int t = idx >> 4;
  int h = t % Hn;
  int bs = t / Hn;
  int b = bs >> 11, s = bs & (Sn - 1);
  float4 v = ((const float4*)src)[idx];
  ushort4 o = make_ushort4(f2bf(v.x * sc), f2bf(v.y * sc), f2bf(v.z * sc), f2bf(v.w * sc));
  size_t off = ((size_t)(b * Hn + h) * Sn + s) * 128 + 64 + d4 * 4;
  *(ushort4*)(dst + off) = o;
}

// ---------------- QKV projection: C[m,n] = sum_k X[m,k] W[n,k] + bias[n] ----------------
// BK=64 global_load_lds staging (XOR-swizzled), LDS-transposed coalesced epilogue.
// 1D grid XCD-swizzled: all 18 (x,z) blocks of one m-tile on one XCD.
__global__ __launch_bounds__(256, 3)
void proj_kernel(const unsigned short* __restrict__ X,   // [8192][768] bf16
                 const unsigned short* __restrict__ Wb,  // [3][768][768] bf16
                 const float* __restrict__ bq, const float* __restrict__ bk, const float* __restrict__ bv,
                 unsigned short* __restrict__ Qc, unsigned short* __restrict__ Kc,
                 unsigned short* __restrict__ Vt) {
  __shared__ __align__(16) unsigned short sMem[16384];   // 32KB: K-loop A|B, then epilogue tile
  unsigned short* const sA = sMem;                       // [128][64]
  unsigned short* const sB = sMem + 8192;                // [128][64]

  // id -> (y on this XCD, then z, then x): X slab read once per XCD, W streamed from L2
  const unsigned id = blockIdx.x;            // [0, 1152)
  const unsigned xcd = id & 7;
  const unsigned slot = id >> 3;             // [0, 144) = 8 y * 18
  const unsigned yloc = slot / 18;
  const unsigned rem = slot - yloc * 18;
  const unsigned z = rem / 6;
  const unsigned xb = rem - z * 6;
  const int m0 = (int)(xcd * 8 + yloc) * 128, n0 = (int)xb * 128;

  const unsigned short* W = Wb + (size_t)z * Dn * Dn;
  const float* bias = (z == 0) ? bq : (z == 1) ? bk : bv;

  const int t = threadIdx.x;
  const int lane = t & 63, wave = t >> 6;
  const int wm = wave >> 1, wn = wave & 1;
  const int quad = lane >> 4, col15 = lane & 15;

  const int srow = lane >> 3, schunk = lane & 7;   // staging: 8 rows/call, 8 chunks/row

  floatx4 acc[4][4];
#pragma unroll
  for (int i = 0; i < 4; i++)
#pragma unroll
    for (int j = 0; j < 4; j++) acc[i][j] = (floatx4){0.f, 0.f, 0.f, 0.f};

  for (int k0 = 0; k0 < Dn; k0 += 64) {
    __syncthreads();
#pragma unroll
    for (int c = 0; c < 4; c++) {
      int row = wave * 32 + c * 8 + srow;
      int g = schunk ^ (row & 7);
      async16(X + (size_t)(m0 + row) * Dn + k0 + g * 8, sA + (wave * 32 + c * 8) * 64);
      async16(W + (size_t)(n0 + row) * Dn + k0 + g * 8, sB + (wave * 32 + c * 8) * 64);
    }
    __syncthreads();
#pragma unroll
    for (int kk = 0; kk < 2; kk++) {
      short8 af[4], bf[4];
      const int slot_ = ((kk * 4 + quad) ^ (col15 & 7)) * 8;
#pragma unroll
      for (int i = 0; i < 4; i++)
        af[i] = *(const short8*)(sA + (wm * 64 + i * 16 + col15) * 64 + slot_);
#pragma unroll
      for (int j = 0; j < 4; j++)
        bf[j] = *(const short8*)(sB + (wn * 64 + j * 16 + col15) * 64 + slot_);
#pragma unroll
      for (int i = 0; i < 4; i++)
#pragma unroll
        for (int j = 0; j < 4; j++)
          acc[i][j] = __builtin_amdgcn_mfma_f32_16x16x32_bf16(af[i], bf[j], acc[i][j], 0, 0, 0);
    }
  }

  __syncthreads();                                  // K-loop LDS reads done; reuse sMem as tile
  const int b = m0 >> 11;                           // blocks never cross batch boundary
  const int s0g = m0 & (Sn - 1);
  const int h0 = n0 >> 6;

  if (z < 2) {
    // ---- Q/K: LDS tile [m][128n], n XOR-swizzled by (m>>2)&3 on bits 4-5 ----
    const float scl = (z == 0) ? QSCL : 1.0f;
    unsigned short* dst0 = (z == 0) ? Qc : Kc;
#pragma unroll
    for (int j = 0; j < 4; j++) {
      int nl = wn * 64 + j * 16 + col15;
      float bias_n = bias[n0 + nl];
#pragma unroll
      for (int i = 0; i < 4; i++) {
        int mb = wm * 64 + i * 16 + quad * 4;
#pragma unroll
        for (int r = 0; r < 4; r++) {
          int m = mb + r;
          sMem[m * 128 + (nl ^ (((m >> 2) & 3) << 4))] = f2bf((acc[i][j][r] + bias_n) * scl);
        }
      }
    }
    __syncthreads();
#pragma unroll
    for (int cc = 0; cc < 8; cc++) {                // 2048 16B chunks, fully coalesced out
      int idx = cc * 256 + t;
      int m = idx >> 4, piece = idx & 15;
      int h = h0 + (piece >> 3), d8 = piece & 7;
      short8 v = *(const short8*)(sMem + m * 128 + (piece ^ (((m >> 2) & 3) << 1)) * 8);
      *(short8*)(dst0 + ((size_t)(b * Hn + h) * Sn + s0g + m) * 128 + d8 * 8) = v;
    }
  } else {
    // ---- V: LDS tile [n][128m], m XOR-swizzled by n&7 on bits 4-6; packed b64 writes ----
#pragma unroll
    for (int j = 0; j < 4; j++) {
      int nl = wn * 64 + j * 16 + col15;
      float bias_n = bias[n0 + nl];
#pragma unroll
      for (int i = 0; i < 4; i++) {
        int mb = wm * 64 + i * 16 + quad * 4;
        ushort4 pk = make_ushort4(f2bf(acc[i][j][0] + bias_n), f2bf(acc[i][j][1] + bias_n),
                                  f2bf(acc[i][j][2] + bias_n), f2bf(acc[i][j][3] + bias_n));
        *(ushort4*)(sMem + nl * 128 + (mb ^ ((nl & 7) << 4))) = pk;
      }
    }
    __syncthreads();
#pragma unroll
    for (int cc = 0; cc < 8; cc++) {                // coalesced Vt rows (256B per 16 lanes)
      int idx = cc * 256 + t;
      int nl = idx >> 4, piece = idx & 15;
      int h = h0 + (nl >> 6), d = nl & 63;
      short8 v = *(const short8*)(sMem + nl * 128 + (piece ^ ((nl & 7) << 1)) * 8);
      *(short8*)(Vt + ((size_t)(b * Hn + h) * 64 + d) * Sn + s0g + piece * 8) = v;
    }
  }
}

// ---------------- flash attention: 128 q-rows/block (2 waves x 64 rows), KT=32 ----------------
// Each K-frag read feeds 4 MFMA (vs 2 at 32 rows/wave) -> LDS bytes per FLOP halved.
// No-max softmax (logits bounded; exact by shift-invariance). 2 barriers/tile.
__global__ __launch_bounds__(128, 2)
void attn_kernel(const unsigned short* __restrict__ Qc,  // [BH][S][128], pre-scaled by QSCL
                 const unsigned short* __restrict__ Kc,  // [BH][S][128]
                 const unsigned short* __restrict__ Vt,  // [BH][64][S]
                 const float* __restrict__ mask,         // [B][S]
                 float* __restrict__ out) {              // [B][S][768]
  constexpr int LDV = 40;                                // sS stride (32 + 8 pad), 8B-aligned rows
  __shared__ __align__(16) unsigned short sKc[32 * 128]; // swizzled, pad-free (8KB)
  __shared__ __align__(16) unsigned short sVt[64 * 32];  // swizzled, pad-free (4KB)
  __shared__ __align__(16) unsigned short sS[128 * LDV]; // P (bf16), wave-private rows (10KB)

  const int t = threadIdx.x;
  const int lane = t & 63, wave = t >> 6;                // 2 waves
  const int quad = lane >> 4, col15 = lane & 15;

  // XCD-aware swizzle: all 16 q-blocks of one bh share id&7 (L2 K/V reuse)
  const int id = blockIdx.x;
  const int slot = id >> 3;
  const int bh = (id & 7) + 8 * (slot >> 4);
  const int q0 = (slot & 15) * 128;
  const int b = bh / Hn, h = bh % Hn;

  // Q fragments: 64 rows/wave x 128 k, in registers for all 64 tiles (64 VGPR)
  short8 aq[4][4];
  const unsigned short* Qbase = Qc + ((size_t)bh * Sn + q0 + wave * 64) * 128;
#pragma unroll
  for (int i = 0; i < 4; i++)
#pragma unroll
    for (int kk = 0; kk < 4; kk++)
      aq[i][kk] = *(const short8*)(Qbase + (size_t)(i * 16 + col15) * 128 + kk * 32 + quad * 8);

  floatx4 O[4][4];
#pragma unroll
  for (int i = 0; i < 4; i++)
#pragma unroll
    for (int j = 0; j < 4; j++) O[i][j] = (floatx4){0.f, 0.f, 0.f, 0.f};
  float lsum[4][4];
#pragma unroll
  for (int i = 0; i < 4; i++)
#pragma unroll
    for (int r = 0; r < 4; r++) lsum[i][r] = 0.f;

  const unsigned short* Kbase = Kc + (size_t)bh * Sn * 128;
  const unsigned short* Vbase = Vt + (size_t)bh * 64 * Sn;
  const float* mbase = mask + (size_t)b * Sn;

  const int krow = lane >> 4, kslot = lane & 15;  // sKc staging: 4 rows/call, 16 chunks/row
  const int vrow = lane >> 2, vchunk = lane & 3;  // sVt staging: 16 rows/call, 4 chunks/row

  for (int kt = 0; kt < Sn / 32; kt++) {
    __syncthreads();                              // prev QK/PV reads done before restage
#pragma unroll
    for (int c = 0; c < 4; c++) {                 // K tile 32x256B, swizzled
      int row = wave * 16 + c * 4 + krow;
      int g = (kslot & 8) | ((kslot ^ row) & 7);
      async16(Kbase + (size_t)(kt * 32 + row) * 128 + g * 8, sKc + (wave * 16 + c * 4) * 128);
    }
#pragma unroll
    for (int c = 0; c < 2; c++) {                 // V^T tile 64x64B, swizzled
      int row = wave * 32 + c * 16 + vrow;
      int g = vchunk ^ (row & 3);
      async16(Vbase + (size_t)row * Sn + kt * 32 + g * 8, sVt + (wave * 32 + c * 16) * 32);
    }
    float mvalL[2];
#pragma unroll
    for (int jk = 0; jk < 2; jk++)
      mvalL[jk] = mbase[kt * 32 + jk * 16 + col15] * LOG2E;
    __syncthreads();

    // ---- S(log2-domain) = Qcat_scaled Kcat^T : each bk_ feeds 4 MFMA ----
    floatx4 sacc[4][2];
#pragma unroll
    for (int i = 0; i < 4; i++) {
      sacc[i][0] = (floatx4){0.f, 0.f, 0.f, 0.f};
      sacc[i][1] = (floatx4){0.f, 0.f, 0.f, 0.f};
    }
#pragma unroll
    for (int jk = 0; jk < 2; jk++)
#pragma unroll
      for (int kk = 0; kk < 4; kk++) {
        int row = jk * 16 + col15;
        int slot_ = (((kk * 4 + quad) & 8) | (((kk * 4 + quad) ^ row) & 7)) * 8;
        short8 bk_ = *(const short8*)(sKc + row * 128 + slot_);
#pragma unroll
        for (int i = 0; i < 4; i++)
          sacc[i][jk] = __builtin_amdgcn_mfma_f32_16x16x32_bf16(aq[i][kk], bk_, sacc[i][jk], 0, 0, 0);
      }

    // ---- no-max softmax: p = exp2(s + mask*log2e), bf16-trunc (l-consistent) ----
#pragma unroll
    for (int i = 0; i < 4; i++) {
      int rowb = wave * 64 + i * 16 + quad * 4;
#pragma unroll
      for (int jk = 0; jk < 2; jk++) {
        int colb = jk * 16 + col15;
#pragma unroll
        for (int r = 0; r < 4; r++) {
          float p = __builtin_amdgcn_exp2f(sacc[i][jk][r] + mvalL[jk]);
          unsigned pu = __float_as_uint(p) & 0xFFFF0000u;
          lsum[i][r] += __uint_as_float(pu);
          sS[(rowb + r) * LDV + colb] = (unsigned short)(pu >> 16);
        }
      }
    }
    // no barrier: sS rows are wave-private; intra-wave LDS RAW is ordered

    // ---- O += P V (K=32, one MFMA chain per (i,j)) ----
#pragma unroll
    for (int i = 0; i < 4; i++) {
      const unsigned short* sp = sS + (wave * 64 + i * 16 + col15) * LDV + quad * 8;
      ushort4 lo = *(const ushort4*)sp;
      ushort4 hi = *(const ushort4*)(sp + 4);
      short8 ap = {(short)lo.x, (short)lo.y, (short)lo.z, (short)lo.w,
                   (short)hi.x, (short)hi.y, (short)hi.z, (short)hi.w};
#pragma unroll
      for (int j = 0; j < 4; j++) {
        int row = j * 16 + col15;
        short8 bv_ = *(const short8*)(sVt + row * 32 + (quad ^ (row & 3)) * 8);
        O[i][j] = __builtin_amdgcn_mfma_f32_16x16x32_bf16(ap, bv_, O[i][j], 0, 0, 0);
      }
    }
  }

  // ---- epilogue: reduce l across the quad's 16 lanes, out = O / l ----
#pragma unroll
  for (int i = 0; i < 4; i++) {
#pragma unroll
    for (int r = 0; r < 4; r++) {
      float s_ = lsum[i][r];
      s_ += __shfl_xor(s_, 1);
      s_ += __shfl_xor(s_, 2);
      s_ += __shfl_xor(s_, 4);
      s_ += __shfl_xor(s_, 8);
      lsum[i][r] = 1.0f / s_;
    }
    int rowb = wave * 64 + i * 16 + quad * 4;
#pragma unroll
    for (int j = 0; j < 4; j++) {
      int dcol = h * 64 + j * 16 + col15;
      float* obase = out + ((size_t)b * Sn + q0 + rowb) * Dn + dcol;
      obase[0 * Dn] = O[i][j][0] * lsum[i][0];
      obase[1 * Dn] = O[i][j][1] * lsum[i][1];
      obase[2 * Dn] = O[i][j][2] * lsum[i][2];
      obase[3 * Dn] = O[i][j][3] * lsum[i][3];
    }
  }
}

extern "C" void kernel_launch(void* const* d_in, const int* in_sizes, int n_in,
                              void* d_out, int out_size, void* d_ws, size_t ws_size,
                              hipStream_t stream) {
  const float* hs   = (const float*)d_in[0];
  const float* lq   = (const float*)d_in[1];
  const float* lk   = (const float*)d_in[2];
  const float* mask = (const float*)d_in[3];
  const float* Wq   = (const float*)d_in[4];
  const float* bq   = (const float*)d_in[5];
  const float* Wk   = (const float*)d_in[6];
  const float* bk   = (const float*)d_in[7];
  const float* Wv   = (const float*)d_in[8];
  const float* bv   = (const float*)d_in[9];
  float* out = (float*)d_out;

  char* ws = (char*)d_ws;
  unsigned short* Xbf = (unsigned short*)ws;                         // [8192][768]
  unsigned short* Wbf = (unsigned short*)(ws + 12582912);            // [3][768][768]
  unsigned short* Qc  = (unsigned short*)(ws + 12582912 + 3538944);  // [48][2048][128]
  unsigned short* Kc  = Qc + (size_t)BHn * Sn * 128;
  unsigned short* Vt  = Kc + (size_t)BHn * Sn * 128;                 // [48][64][2048]

  cast_hs_kernel<<<6144, 256, 0, stream>>>(hs, Xbf, 1572864);
  cast_w_kernel<<<dim3(576, 3), 256, 0, stream>>>(Wq, Wk, Wv, Wbf);
  pack_layout_kernel<<<dim3(6144, 2), 256, 0, stream>>>(lq, lk, Qc, Kc);
  proj_kernel<<<1152, 256, 0, stream>>>(Xbf, Wbf, bq, bk, bv, Qc, Kc, Vt);
  attn_kernel<<<768, 128, 0, stream>>>(Qc, Kc, Vt, mask, out);
}

// Round 5
// 272.934 us; speedup vs baseline: 1.0760x; 1.0760x over previous
//
#include <hip/hip_runtime.h>

// GMLLM dual-stream self-attention, MI355X/gfx950.  Round 5:
//  - attn: S^T formulation — QK^T computed operand-swapped so exp(S) feeds PV
//          *directly from registers* via v_mfma_f32_16x16x16_bf16 (C-layout of S^T
//          == B-layout of x16 MFMA). No P LDS round-trip. Mask row pre-staged.
//          O^T epilogue -> float4 stores. 4-wave blocks, 3 blocks/CU.
//  - proj: reverted to R3 exactly (R4 swizzle/bounds regressed).

typedef __attribute__((ext_vector_type(8))) short short8;   // 8 x bf16 MFMA A/B frag (x32)
typedef __attribute__((ext_vector_type(4))) short short4v;  // 4 x bf16 MFMA A/B frag (x16)
typedef __attribute__((ext_vector_type(4))) float floatx4;  // MFMA C/D frag

#define LOG2E 1.4426950408889634f
#define QSCL 0.18033688011112042f   /* 0.125 * log2(e) */

static constexpr int Sn = 2048, Dn = 768, Hn = 12, BHn = 48;

__device__ __forceinline__ unsigned short f2bf(float f) {
  unsigned u = __float_as_uint(f);
  u += 0x7FFFu + ((u >> 16) & 1u);          // RNE
  return (unsigned short)(u >> 16);
}

typedef const __attribute__((address_space(1))) unsigned int* gas_t;
typedef __attribute__((address_space(3))) unsigned int* las_t;
__device__ __forceinline__ void async16(const void* g, void* l) {
  // async 16B/lane global->LDS; LDS dest = wave-uniform base + lane*16
  __builtin_amdgcn_global_load_lds((gas_t)g, (las_t)l, 16, 0, 0);
}

__device__ __forceinline__ floatx4 mfma16(short4v a, short4v b, floatx4 c) {
#if __has_builtin(__builtin_amdgcn_mfma_f32_16x16x16bf16_1k)
  return __builtin_amdgcn_mfma_f32_16x16x16bf16_1k(a, b, c, 0, 0, 0);
#else
  asm volatile("v_mfma_f32_16x16x16_bf16 %0, %1, %2, %0" : "+v"(c) : "v"(a), "v"(b));
  return c;
#endif
}

// ---------------- cast hidden_states f32 -> bf16 (row-major [8192][768]) ----------------
__global__ void cast_hs_kernel(const float* __restrict__ in, unsigned short* __restrict__ out, int n4) {
  int i = blockIdx.x * 256 + threadIdx.x;
  if (i >= n4) return;
  float4 v = ((const float4*)in)[i];
  ushort4 o = make_ushort4(f2bf(v.x), f2bf(v.y), f2bf(v.z), f2bf(v.w));
  ((ushort4*)out)[i] = o;
}

// ---------------- cast Wq/Wk/Wv f32 -> bf16, stacked [3][768][768] ----------------
__global__ void cast_w_kernel(const float* __restrict__ w0, const float* __restrict__ w1,
                              const float* __restrict__ w2, unsigned short* __restrict__ out) {
  int i = blockIdx.x * 256 + threadIdx.x;
  const float* src = (blockIdx.y == 0) ? w0 : (blockIdx.y == 1) ? w1 : w2;
  float4 v = ((const float4*)src)[i];
  ushort4 o = make_ushort4(f2bf(v.x), f2bf(v.y), f2bf(v.z), f2bf(v.w));
  ((ushort4*)(out + (size_t)blockIdx.y * Dn * Dn))[i] = o;
}

// ---------------- pack layout_q (pre-scaled) / layout_k into upper half of Qc/Kc ----------------
__global__ void pack_layout_kernel(const float* __restrict__ lq, const float* __restrict__ lk,
                                   unsigned short* __restrict__ Qc, unsigned short* __restrict__ Kc) {
  int idx = blockIdx.x * 256 + threadIdx.x;
  const float* src = blockIdx.y ? lk : lq;
  unsigned short* dst = blockIdx.y ? Kc : Qc;
  const float sc = blockIdx.y ? 1.0f : QSCL;
  int d4 = idx & 15;
  int t = idx >> 4;
  int h = t % Hn;
  int bs = t / Hn;
  int b = bs >> 11, s = bs & (Sn - 1);
  float4 v = ((const float4*)src)[idx];
  ushort4 o = make_ushort4(f2bf(v.x * sc), f2bf(v.y * sc), f2bf(v.z * sc), f2bf(v.w * sc));
  size_t off = ((size_t)(b * Hn + h) * Sn + s) * 128 + 64 + d4 * 4;
  *(ushort4*)(dst + off) = o;
}

// ---------------- QKV projection (R3 form): C[m,n] = sum_k X[m,k] W[n,k] + bias[n] ----------------
__global__ __launch_bounds__(256, 2)
void proj_kernel(const unsigned short* __restrict__ X,   // [8192][768] bf16
                 const unsigned short* __restrict__ Wb,  // [3][768][768] bf16
                 const float* __restrict__ bq, const float* __restrict__ bk, const float* __restrict__ bv,
                 unsigned short* __restrict__ Qc, unsigned short* __restrict__ Kc,
                 unsigned short* __restrict__ Vt) {
  __shared__ __align__(16) unsigned short sMem[16384];   // 32KB: K-loop A|B, then epilogue tile
  unsigned short* const sA = sMem;                       // [128][64]
  unsigned short* const sB = sMem + 8192;                // [128][64]

  const int z = blockIdx.z;
  const unsigned short* W = Wb + (size_t)z * Dn * Dn;
  const float* bias = (z == 0) ? bq : (z == 1) ? bk : bv;

  const int t = threadIdx.x;
  const int lane = t & 63, wave = t >> 6;
  const int wm = wave >> 1, wn = wave & 1;
  const int quad = lane >> 4, col15 = lane & 15;
  const int m0 = blockIdx.y * 128, n0 = blockIdx.x * 128;

  const int srow = lane >> 3, schunk = lane & 7;   // staging: 8 rows/call, 8 chunks/row

  floatx4 acc[4][4];
#pragma unroll
  for (int i = 0; i < 4; i++)
#pragma unroll
    for (int j = 0; j < 4; j++) acc[i][j] = (floatx4){0.f, 0.f, 0.f, 0.f};

  for (int k0 = 0; k0 < Dn; k0 += 64) {
    __syncthreads();
#pragma unroll
    for (int c = 0; c < 4; c++) {
      int row = wave * 32 + c * 8 + srow;
      int g = schunk ^ (row & 7);
      async16(X + (size_t)(m0 + row) * Dn + k0 + g * 8, sA + (wave * 32 + c * 8) * 64);
      async16(W + (size_t)(n0 + row) * Dn + k0 + g * 8, sB + (wave * 32 + c * 8) * 64);
    }
    __syncthreads();
#pragma unroll
    for (int kk = 0; kk < 2; kk++) {
      short8 af[4], bf[4];
      const int slot_ = ((kk * 4 + quad) ^ (col15 & 7)) * 8;
#pragma unroll
      for (int i = 0; i < 4; i++)
        af[i] = *(const short8*)(sA + (wm * 64 + i * 16 + col15) * 64 + slot_);
#pragma unroll
      for (int j = 0; j < 4; j++)
        bf[j] = *(const short8*)(sB + (wn * 64 + j * 16 + col15) * 64 + slot_);
#pragma unroll
      for (int i = 0; i < 4; i++)
#pragma unroll
        for (int j = 0; j < 4; j++)
          acc[i][j] = __builtin_amdgcn_mfma_f32_16x16x32_bf16(af[i], bf[j], acc[i][j], 0, 0, 0);
    }
  }

  __syncthreads();                                  // K-loop LDS reads done; reuse sMem as tile
  const int b = m0 >> 11;                           // blocks never cross batch boundary
  const int s0g = m0 & (Sn - 1);
  const int h0 = n0 >> 6;

  if (z < 2) {
    // ---- Q/K: LDS tile [m][128n], n XOR-swizzled by (m>>2)&3 on bits 4-5 ----
    const float scl = (z == 0) ? QSCL : 1.0f;
    unsigned short* dst0 = (z == 0) ? Qc : Kc;
#pragma unroll
    for (int j = 0; j < 4; j++) {
      int nl = wn * 64 + j * 16 + col15;
      float bias_n = bias[n0 + nl];
#pragma unroll
      for (int i = 0; i < 4; i++) {
        int mb = wm * 64 + i * 16 + quad * 4;
#pragma unroll
        for (int r = 0; r < 4; r++) {
          int m = mb + r;
          sMem[m * 128 + (nl ^ (((m >> 2) & 3) << 4))] = f2bf((acc[i][j][r] + bias_n) * scl);
        }
      }
    }
    __syncthreads();
#pragma unroll
    for (int cc = 0; cc < 8; cc++) {                // 2048 16B chunks, fully coalesced out
      int idx = cc * 256 + t;
      int m = idx >> 4, piece = idx & 15;
      int h = h0 + (piece >> 3), d8 = piece & 7;
      short8 v = *(const short8*)(sMem + m * 128 + (piece ^ (((m >> 2) & 3) << 1)) * 8);
      *(short8*)(dst0 + ((size_t)(b * Hn + h) * Sn + s0g + m) * 128 + d8 * 8) = v;
    }
  } else {
    // ---- V: LDS tile [n][128m], m XOR-swizzled by n&7 on bits 4-6; packed b64 writes ----
#pragma unroll
    for (int j = 0; j < 4; j++) {
      int nl = wn * 64 + j * 16 + col15;
      float bias_n = bias[n0 + nl];
#pragma unroll
      for (int i = 0; i < 4; i++) {
        int mb = wm * 64 + i * 16 + quad * 4;
        ushort4 pk = make_ushort4(f2bf(acc[i][j][0] + bias_n), f2bf(acc[i][j][1] + bias_n),
                                  f2bf(acc[i][j][2] + bias_n), f2bf(acc[i][j][3] + bias_n));
        *(ushort4*)(sMem + nl * 128 + (mb ^ ((nl & 7) << 4))) = pk;
      }
    }
    __syncthreads();
#pragma unroll
    for (int cc = 0; cc < 8; cc++) {                // coalesced Vt rows (256B per 16 lanes)
      int idx = cc * 256 + t;
      int nl = idx >> 4, piece = idx & 15;
      int h = h0 + (nl >> 6), d = nl & 63;
      short8 v = *(const short8*)(sMem + nl * 128 + (piece ^ ((nl & 7) << 1)) * 8);
      *(short8*)(Vt + ((size_t)(b * Hn + h) * 64 + d) * Sn + s0g + piece * 8) = v;
    }
  }
}

// ---------------- flash attention, S^T formulation: 128 q-rows/block, KT=64 ----------------
// S^T = K·Q^T (x32 MFMA, operands swapped). C-layout of S^T: lane holds q=lane&15,
// keys=quad*4+reg — exactly the B-operand layout of v_mfma_f32_16x16x16_bf16, so
// P = exp2(S^T + mask) feeds O^T = V^T · P directly from registers. No P LDS trip.
__global__ __launch_bounds__(256, 3)
void attn_kernel(const unsigned short* __restrict__ Qc,  // [BH][S][128], pre-scaled by QSCL
                 const unsigned short* __restrict__ Kc,  // [BH][S][128]
                 const unsigned short* __restrict__ Vt,  // [BH][64][S]
                 const float* __restrict__ mask,         // [B][S]
                 float* __restrict__ out) {              // [B][S][768]
  __shared__ __align__(16) unsigned short sKc[64 * 128]; // swizzled, pad-free (16KB)
  __shared__ __align__(16) unsigned short sVt[64 * 64];  // swizzled, pad-free (8KB)
  __shared__ __align__(16) float sMask[Sn];              // whole mask row (8KB)

  const int t = threadIdx.x;
  const int lane = t & 63, wave = t >> 6;
  const int quad = lane >> 4, col15 = lane & 15;

  // XCD-aware swizzle: all 16 q-blocks of one bh share id&7 (L2 K/V reuse)
  const int id = blockIdx.x;
  const int slot = id >> 3;
  const int bh = (id & 7) + 8 * (slot >> 4);
  const int q0 = (slot & 15) * 128;
  const int b = bh / Hn, h = bh % Hn;

  const float* mbase = mask + (size_t)b * Sn;
  // stage the whole mask row once (drained by the loop's first __syncthreads)
#pragma unroll
  for (int c = 0; c < 2; c++)
    async16(mbase + (c * 256 + wave * 64 + lane) * 4, sMask + (c * 256 + wave * 64) * 4);

  // Q fragments: 32 rows/wave x 128 k, registers for all 32 tiles (B-operand of S^T)
  short8 aq[2][4];
  const unsigned short* Qbase = Qc + ((size_t)bh * Sn + q0 + wave * 32) * 128;
#pragma unroll
  for (int jq = 0; jq < 2; jq++)
#pragma unroll
    for (int kk = 0; kk < 4; kk++)
      aq[jq][kk] = *(const short8*)(Qbase + (size_t)(jq * 16 + col15) * 128 + kk * 32 + quad * 8);

  floatx4 OT[4][2];                                // O^T[d-tile][q-tile]
#pragma unroll
  for (int i = 0; i < 4; i++) {
    OT[i][0] = (floatx4){0.f, 0.f, 0.f, 0.f};
    OT[i][1] = (floatx4){0.f, 0.f, 0.f, 0.f};
  }
  float lsum[2] = {0.f, 0.f};

  const unsigned short* Kbase = Kc + (size_t)bh * Sn * 128;
  const unsigned short* Vbase = Vt + (size_t)bh * 64 * Sn;

  const int krow = lane >> 4, kslot = lane & 15;  // sKc staging: 4 rows/call, 16 chunks/row
  const int vrow = lane >> 3, vslot = lane & 7;   // sVt staging: 8 rows/call, 8 chunks/row

  for (int kt = 0; kt < Sn / 64; kt++) {
    __syncthreads();                              // prev tile reads done before restage
#pragma unroll
    for (int c = 0; c < 4; c++) {                 // K tile 64x256B, swizzled
      int row = wave * 16 + c * 4 + krow;
      int g = (kslot & 8) | ((kslot ^ row) & 7);
      async16(Kbase + (size_t)(kt * 64 + row) * 128 + g * 8, sKc + (wave * 16 + c * 4) * 128);
    }
#pragma unroll
    for (int c = 0; c < 2; c++) {                 // V^T tile 64x128B, swizzled
      int row = wave * 16 + c * 8 + vrow;
      int g = vslot ^ (row & 7);
      async16(Vbase + (size_t)row * Sn + kt * 64 + g * 8, sVt + (wave * 16 + c * 8) * 64);
    }
    __syncthreads();

    // ---- S^T = K Q^T (log2-domain; QSCL*log2e folded into Q) ----
    floatx4 sacc[4][2];
#pragma unroll
    for (int jk = 0; jk < 4; jk++) {
      sacc[jk][0] = (floatx4){0.f, 0.f, 0.f, 0.f};
      sacc[jk][1] = (floatx4){0.f, 0.f, 0.f, 0.f};
#pragma unroll
      for (int kk = 0; kk < 4; kk++) {
        int gr = kk * 4 + quad;
        int slot_ = ((gr & 8) | ((gr ^ col15) & 7)) * 8;
        short8 kf = *(const short8*)(sKc + (jk * 16 + col15) * 128 + slot_);
        sacc[jk][0] = __builtin_amdgcn_mfma_f32_16x16x32_bf16(kf, aq[0][kk], sacc[jk][0], 0, 0, 0);
        sacc[jk][1] = __builtin_amdgcn_mfma_f32_16x16x32_bf16(kf, aq[1][kk], sacc[jk][1], 0, 0, 0);
      }
    }

    // ---- P = exp2(S^T + mask*log2e), bf16-trunc (l-consistent), packed in regs ----
    short4v pvb[2][4];                            // [q-tile][key-block] B-frags for PV
#pragma unroll
    for (int jk = 0; jk < 4; jk++) {
      float4 mv = *(const float4*)(sMask + kt * 64 + jk * 16 + quad * 4);  // quad-broadcast
      float m0 = mv.x * LOG2E, m1 = mv.y * LOG2E, m2 = mv.z * LOG2E, m3 = mv.w * LOG2E;
#pragma unroll
      for (int jq = 0; jq < 2; jq++) {
        unsigned u0 = __float_as_uint(__builtin_amdgcn_exp2f(sacc[jk][jq][0] + m0)) & 0xFFFF0000u;
        unsigned u1 = __float_as_uint(__builtin_amdgcn_exp2f(sacc[jk][jq][1] + m1)) & 0xFFFF0000u;
        unsigned u2 = __float_as_uint(__builtin_amdgcn_exp2f(sacc[jk][jq][2] + m2)) & 0xFFFF0000u;
        unsigned u3 = __float_as_uint(__builtin_amdgcn_exp2f(sacc[jk][jq][3] + m3)) & 0xFFFF0000u;
        lsum[jq] += (__uint_as_float(u0) + __uint_as_float(u1)) +
                    (__uint_as_float(u2) + __uint_as_float(u3));
        int2 pk;                                  // pair-pack: [p1|p0], [p3|p2]
        pk.x = (int)((u0 >> 16) | u1);
        pk.y = (int)((u2 >> 16) | u3);
        pvb[jq][jk] = *(short4v*)&pk;
      }
    }

    // ---- O^T += V^T P  (x16 MFMA, P straight from registers) ----
#pragma unroll
    for (int i = 0; i < 4; i++) {
      int row = i * 16 + col15;
#pragma unroll
      for (int jk = 0; jk < 4; jk++) {
        int gi = (jk * 2 + (quad >> 1)) ^ (row & 7);
        short4v vf = *(const short4v*)(sVt + row * 64 + gi * 8 + (quad & 1) * 4);
        OT[i][0] = mfma16(vf, pvb[0][jk], OT[i][0]);
        OT[i][1] = mfma16(vf, pvb[1][jk], OT[i][1]);
      }
    }
  }

  // ---- epilogue: reduce l across quads (lanes c,c+16,c+32,c+48), O^T/l -> float4 stores ----
  float linv[2];
#pragma unroll
  for (int jq = 0; jq < 2; jq++) {
    float s_ = lsum[jq];
    s_ += __shfl_xor(s_, 16);
    s_ += __shfl_xor(s_, 32);
    linv[jq] = 1.0f / s_;
  }
#pragma unroll
  for (int jq = 0; jq < 2; jq++) {
    float* obase = out + ((size_t)b * Sn + q0 + wave * 32 + jq * 16 + col15) * Dn + h * 64 + quad * 4;
#pragma unroll
    for (int i = 0; i < 4; i++) {
      float4 o;
      o.x = OT[i][jq][0] * linv[jq];
      o.y = OT[i][jq][1] * linv[jq];
      o.z = OT[i][jq][2] * linv[jq];
      o.w = OT[i][jq][3] * linv[jq];
      *(float4*)(obase + i * 16) = o;             // d = h*64 + i*16 + quad*4 + {0..3}
    }
  }
}

extern "C" void kernel_launch(void* const* d_in, const int* in_sizes, int n_in,
                              void* d_out, int out_size, void* d_ws, size_t ws_size,
                              hipStream_t stream) {
  const float* hs   = (const float*)d_in[0];
  const float* lq   = (const float*)d_in[1];
  const float* lk   = (const float*)d_in[2];
  const float* mask = (const float*)d_in[3];
  const float* Wq   = (const float*)d_in[4];
  const float* bq   = (const float*)d_in[5];
  const float* Wk   = (const float*)d_in[6];
  const float* bk   = (const float*)d_in[7];
  const float* Wv   = (const float*)d_in[8];
  const float* bv   = (const float*)d_in[9];
  float* out = (float*)d_out;

  char* ws = (char*)d_ws;
  unsigned short* Xbf = (unsigned short*)ws;                         // [8192][768]
  unsigned short* Wbf = (unsigned short*)(ws + 12582912);            // [3][768][768]
  unsigned short* Qc  = (unsigned short*)(ws + 12582912 + 3538944);  // [48][2048][128]
  unsigned short* Kc  = Qc + (size_t)BHn * Sn * 128;
  unsigned short* Vt  = Kc + (size_t)BHn * Sn * 128;                 // [48][64][2048]

  cast_hs_kernel<<<6144, 256, 0, stream>>>(hs, Xbf, 1572864);
  cast_w_kernel<<<dim3(576, 3), 256, 0, stream>>>(Wq, Wk, Wv, Wbf);
  pack_layout_kernel<<<dim3(6144, 2), 256, 0, stream>>>(lq, lk, Qc, Kc);
  proj_kernel<<<dim3(6, 64, 3), 256, 0, stream>>>(Xbf, Wbf, bq, bk, bv, Qc, Kc, Vt);
  attn_kernel<<<768, 256, 0, stream>>>(Qc, Kc, Vt, mask, out);
}